// Round 4
// baseline (188.907 us; speedup 1.0000x reference)
//
#include <hip/hip_runtime.h>
#include <math.h>

#define Bn 8
#define Cn 512
#define Kn 64
#define C4n 128
#define Nn 4096

typedef short bf16x8 __attribute__((ext_vector_type(8)));
typedef float f32x4  __attribute__((ext_vector_type(4)));
typedef unsigned short u16;

__device__ __forceinline__ u16 f2bf(float f) {
    union { float f; unsigned u; } v; v.f = f;
    unsigned r = v.u + 0x7FFF + ((v.u >> 16) & 1);   // RNE
    return (u16)(r >> 16);
}

// ---------------------------------------------------------------------------
// W2cm[c'][c] = sum_d wk[d,c'] * wq[d,c]
// m0[c]      = sum_d bk[d] * wq[d,c]
// wbv[c']    = sum_d bq[d] * wk[d,c'] ; wbv[512] = sum_d bq[d]*bk[d]
__global__ __launch_bounds__(256) void mk_W2_kernel(
    const float* __restrict__ wq, const float* __restrict__ wk,
    const float* __restrict__ bq, const float* __restrict__ bk,
    float* __restrict__ W2cm, float* __restrict__ m0, float* __restrict__ wbv)
{
    const int cp = blockIdx.x;
    const int t  = threadIdx.x;
    float acc0 = 0.f, acc1 = 0.f;
    for (int d = 0; d < C4n; ++d) {
        float wkv = wk[(size_t)d * Cn + cp];
        acc0 += wkv * wq[(size_t)d * Cn + t];
        acc1 += wkv * wq[(size_t)d * Cn + t + 256];
    }
    W2cm[(size_t)cp * Cn + t]       = acc0;
    W2cm[(size_t)cp * Cn + t + 256] = acc1;
    if (blockIdx.x == 0) {
        float a0 = 0.f, a1 = 0.f;
        for (int d = 0; d < C4n; ++d) {
            float bkv = bk[d];
            a0 += bkv * wq[(size_t)d * Cn + t];
            a1 += bkv * wq[(size_t)d * Cn + t + 256];
        }
        m0[t] = a0; m0[t + 256] = a1;
    }
    if (t == 0) {
        float a = 0.f;
        for (int d = 0; d < C4n; ++d) a += bq[d] * wk[(size_t)d * Cn + cp];
        wbv[cp] = a;
    }
    if (blockIdx.x == 0 && t == 0) {
        float a = 0.f;
        for (int d = 0; d < C4n; ++d) a += bq[d] * bk[d];
        wbv[512] = a;
    }
}

// ---------------------------------------------------------------------------
// wvT[c'][c] = wv[c][c']
__global__ __launch_bounds__(256) void transpose_wv_kernel(
    const float* __restrict__ wv, float* __restrict__ wvT)
{
    __shared__ float tile[64 * 68];
    const int bx = blockIdx.x & 7;
    const int by = blockIdx.x >> 3;
    const int t  = threadIdx.x;
    {
        const int r  = t >> 2;
        const int cb = (t & 3) * 16;
        const float* src = wv + (size_t)(by * 64 + r) * Cn + bx * 64 + cb;
        #pragma unroll
        for (int u = 0; u < 4; ++u)
            *(float4*)&tile[r * 68 + cb + 4 * u] = *(const float4*)(src + 4 * u);
    }
    __syncthreads();
    {
        const int cpl = t >> 2;
        const int cb  = (t & 3) * 16;
        float* dst = wvT + (size_t)(bx * 64 + cpl) * Cn + by * 64 + cb;
        #pragma unroll
        for (int u = 0; u < 16; u += 4) {
            float4 v;
            v.x = tile[(cb + u + 0) * 68 + cpl];
            v.y = tile[(cb + u + 1) * 68 + cpl];
            v.z = tile[(cb + u + 2) * 68 + cpl];
            v.w = tile[(cb + u + 3) * 68 + cpl];
            *(float4*)(dst + u) = v;
        }
    }
}

// ---------------------------------------------------------------------------
// Batched tiled GEMM: acc[c,k] = sum_c' W[c'][c] * y[b,k,c'] + bias[c]
// sel 0: (y1, wvT, bv)  -> pv1h[b][c][k]  bf16
// sel 1: (y2, wvT, bv)  -> pv2h[b][c][k]  bf16
// sel 2: (y2, W2cm, m0) -> Mth[b][k][c]   bf16 (transposed store)
__global__ __launch_bounds__(256) void proj_gemm_kernel(
    const float* __restrict__ y1, const float* __restrict__ y2,
    const float* __restrict__ wvT, const float* __restrict__ W2cm,
    const float* __restrict__ bv, const float* __restrict__ m0,
    u16* __restrict__ pv1h, u16* __restrict__ pv2h, u16* __restrict__ Mth)
{
    __shared__ float Ws[32 * 68];
    __shared__ float Ys[32 * 68];
    const int sel = blockIdx.z;
    const int b   = blockIdx.y;
    const int ct  = blockIdx.x;
    const float* y    = (sel == 0) ? y1 : y2;
    const float* W    = (sel == 2) ? W2cm : wvT;
    const float* bias = (sel == 2) ? m0 : bv;

    const int t   = threadIdx.x;
    const int wr  = t >> 3;
    const int wcb = (t & 7) * 8;
    const int yk  = t >> 2;
    const int ycb = (t & 3) * 8;
    const int kq  = t & 15;
    const int cg  = t >> 4;

    float e[4][4] = {{0.f}};
    for (int c0 = 0; c0 < Cn; c0 += 32) {
        __syncthreads();
        {
            const float* wsrc = W + (size_t)(c0 + wr) * Cn + ct * 64 + wcb;
            float4 w0 = *(const float4*)wsrc;
            float4 w1 = *(const float4*)(wsrc + 4);
            *(float4*)&Ws[wr * 68 + wcb]     = w0;
            *(float4*)&Ws[wr * 68 + wcb + 4] = w1;
            const float* ysrc = y + (size_t)(b * Kn + yk) * Cn + c0 + ycb;
            float4 a0 = *(const float4*)ysrc;
            float4 a1 = *(const float4*)(ysrc + 4);
            Ys[(ycb + 0) * 68 + yk] = a0.x;
            Ys[(ycb + 1) * 68 + yk] = a0.y;
            Ys[(ycb + 2) * 68 + yk] = a0.z;
            Ys[(ycb + 3) * 68 + yk] = a0.w;
            Ys[(ycb + 4) * 68 + yk] = a1.x;
            Ys[(ycb + 5) * 68 + yk] = a1.y;
            Ys[(ycb + 6) * 68 + yk] = a1.z;
            Ys[(ycb + 7) * 68 + yk] = a1.w;
        }
        __syncthreads();
        #pragma unroll 8
        for (int cc = 0; cc < 32; ++cc) {
            float4 wv4 = *(const float4*)&Ws[cc * 68 + 4 * cg];
            float4 yv4 = *(const float4*)&Ys[cc * 68 + 4 * kq];
            float wr_[4] = {wv4.x, wv4.y, wv4.z, wv4.w};
            float yr_[4] = {yv4.x, yv4.y, yv4.z, yv4.w};
            #pragma unroll
            for (int i = 0; i < 4; ++i)
                #pragma unroll
                for (int j = 0; j < 4; ++j)
                    e[i][j] += wr_[i] * yr_[j];
        }
    }
    if (sel < 2) {
        u16* out = sel ? pv2h : pv1h;
        #pragma unroll
        for (int i = 0; i < 4; ++i) {
            int c = ct * 64 + 4 * cg + i;
            float bb = bias[c];
            ushort4 o;
            o.x = f2bf(e[i][0] + bb); o.y = f2bf(e[i][1] + bb);
            o.z = f2bf(e[i][2] + bb); o.w = f2bf(e[i][3] + bb);
            *(ushort4*)&out[((size_t)(b * Cn + c) << 6) + 4 * kq] = o;
        }
    } else {
        int cbase = ct * 64 + 4 * cg;
        float b0 = bias[cbase], b1 = bias[cbase + 1];
        float b2 = bias[cbase + 2], b3 = bias[cbase + 3];
        #pragma unroll
        for (int j = 0; j < 4; ++j) {
            int k = 4 * kq + j;
            ushort4 o;
            o.x = f2bf(e[0][j] + b0); o.y = f2bf(e[1][j] + b1);
            o.z = f2bf(e[2][j] + b2); o.w = f2bf(e[3][j] + b3);
            *(ushort4*)&Mth[((size_t)(b * Kn + k) << 9) + cbase] = o;
        }
    }
}

// ---------------------------------------------------------------------------
// e0[b,k] = sum_c' y2[b,k,c'] * wbv[c'] + wbv[512]
__global__ __launch_bounds__(512) void e0_kernel(
    const float* __restrict__ y2, const float* __restrict__ wbv,
    float* __restrict__ e0)
{
    const int b = blockIdx.x;
    const int t = threadIdx.x;
    const int k = t >> 3;
    const int cb = (t & 7) * 64;
    const float* yr = y2 + (size_t)(b * Kn + k) * Cn + cb;
    const float* wr = wbv + cb;
    float acc = 0.f;
    #pragma unroll 4
    for (int i = 0; i < 64; i += 4) {
        float4 yv = *(const float4*)(yr + i);
        float4 wv4 = *(const float4*)(wr + i);
        acc += yv.x * wv4.x + yv.y * wv4.y + yv.z * wv4.z + yv.w * wv4.w;
    }
    acc += __shfl_xor(acc, 1);
    acc += __shfl_xor(acc, 2);
    acc += __shfl_xor(acc, 4);
    if ((t & 7) == 0) e0[b * Kn + k] = acc + wbv[512];
}

// ---------------------------------------------------------------------------
// Energy + softmax: attG[b][n][k] = softmax_k |x2ᵀ·M + e0|  (bf16, normalized)
// Grid 512 (b = id&7, 64-n tile = id>>3), 256 threads.
__global__ __launch_bounds__(256) void energy_softmax_kernel(
    const float* __restrict__ x2, const u16* __restrict__ Mth,
    const float* __restrict__ e0, u16* __restrict__ attG)
{
    __shared__ float Xs[32 * 68];

    const int id   = blockIdx.x;
    const int b    = id & 7;
    const int n0   = (id >> 3) * 64;
    const int t    = threadIdx.x;
    const int lane = t & 63;
    const int wid  = t >> 6;
    const int lr   = lane & 15;
    const int lg   = lane >> 4;
    const int wn0  = wid * 16;

    f32x4 eacc[4];
    #pragma unroll
    for (int kt = 0; kt < 4; ++kt) eacc[kt] = (f32x4){0.f, 0.f, 0.f, 0.f};

    const int sc = t >> 3;
    const int sb = (t & 7) * 8;

    // register prefetch of tile c0=0
    const float* src0 = x2 + (((size_t)(b * Cn + sc)) << 12) + n0 + sb;
    float4 r0 = *(const float4*)src0;
    float4 r1 = *(const float4*)(src0 + 4);

    for (int c0 = 0; c0 < Cn; c0 += 32) {
        __syncthreads();
        *(float4*)&Xs[sc * 68 + sb]     = r0;
        *(float4*)&Xs[sc * 68 + sb + 4] = r1;
        __syncthreads();
        if (c0 + 32 < Cn) {   // issue next tile early (hide HBM under MFMA)
            const float* src = x2 + (((size_t)(b * Cn + c0 + 32 + sc)) << 12) + n0 + sb;
            r0 = *(const float4*)src;
            r1 = *(const float4*)(src + 4);
        }
        bf16x8 av;
        #pragma unroll
        for (int j = 0; j < 8; ++j)
            av[j] = (short)f2bf(Xs[(lg * 8 + j) * 68 + wn0 + lr]);
        const u16* mb = Mth + ((size_t)b << 15) + (size_t)lr * Cn + c0 + lg * 8;
        #pragma unroll
        for (int kt = 0; kt < 4; ++kt) {
            bf16x8 bv = *(const bf16x8*)(mb + ((size_t)kt << 13));
            eacc[kt] = __builtin_amdgcn_mfma_f32_16x16x32_bf16(av, bv, eacc[kt], 0, 0, 0);
        }
    }

    // softmax over k of |energy + e0|, write normalized bf16 att
    float e0v[4];
    #pragma unroll
    for (int kt = 0; kt < 4; ++kt) e0v[kt] = e0[b * Kn + lr + 16 * kt];
    #pragma unroll
    for (int reg = 0; reg < 4; ++reg) {
        float a[4];
        #pragma unroll
        for (int kt = 0; kt < 4; ++kt) a[kt] = fabsf(eacc[kt][reg] + e0v[kt]);
        float mx = fmaxf(fmaxf(a[0], a[1]), fmaxf(a[2], a[3]));
        #pragma unroll
        for (int m = 1; m <= 8; m <<= 1) mx = fmaxf(mx, __shfl_xor(mx, m));
        float s = 0.f;
        #pragma unroll
        for (int kt = 0; kt < 4; ++kt) { a[kt] = __expf(a[kt] - mx); s += a[kt]; }
        #pragma unroll
        for (int m = 1; m <= 8; m <<= 1) s += __shfl_xor(s, m);
        float inv = 1.0f / s;
        const int n = n0 + wn0 + lg * 4 + reg;
        u16* dst = attG + (((size_t)b << 18) | ((size_t)n << 6));
        #pragma unroll
        for (int kt = 0; kt < 4; ++kt)
            dst[lr + 16 * kt] = f2bf(a[kt] * inv);
    }
}

// ---------------------------------------------------------------------------
// Streaming out kernel: out = scale * pv · attᵀ + x  (both outputs).
// Grid dim3(64 nt, 8 ct, 8 b), 256 threads (4 waves), no LDS.
__global__ __launch_bounds__(256) void out_kernel(
    const float* __restrict__ x1, const float* __restrict__ x2,
    const u16* __restrict__ pv1h, const u16* __restrict__ pv2h,
    const u16* __restrict__ attG,
    const float* __restrict__ scale, const float* __restrict__ scale1,
    float* __restrict__ out1, float* __restrict__ out2)
{
    const int n0   = blockIdx.x * 64;
    const int ct   = blockIdx.y;
    const int b    = blockIdx.z;
    const int t    = threadIdx.x;
    const int lane = t & 63;
    const int wid  = t >> 6;
    const int lr   = lane & 15;
    const int lg   = lane >> 4;
    const int wc   = ct * 64 + wid * 16;    // wave's 16-c stripe

    // A-frags: pv[b][c = wc+lr][k], k-chunks at lg*8 and 32+lg*8
    const u16* p1 = pv1h + (((size_t)(b * Cn + wc + lr)) << 6) + lg * 8;
    const u16* p2 = pv2h + (((size_t)(b * Cn + wc + lr)) << 6) + lg * 8;
    bf16x8 a1[2], a2[2];
    a1[0] = *(const bf16x8*)p1;  a1[1] = *(const bf16x8*)(p1 + 32);
    a2[0] = *(const bf16x8*)p2;  a2[1] = *(const bf16x8*)(p2 + 32);

    // B-frags: att[b][n = n0+nt*16+lr][k], same k-chunks; then MFMA
    f32x4 acc1[4], acc2[4];
    #pragma unroll
    for (int nt = 0; nt < 4; ++nt) {
        const u16* ab = attG + (((size_t)b << 18) | ((size_t)(n0 + nt * 16 + lr) << 6)) + lg * 8;
        bf16x8 b0 = *(const bf16x8*)ab;
        bf16x8 b1 = *(const bf16x8*)(ab + 32);
        f32x4 z = (f32x4){0.f, 0.f, 0.f, 0.f};
        acc1[nt] = __builtin_amdgcn_mfma_f32_16x16x32_bf16(a1[0], b0, z, 0, 0, 0);
        acc1[nt] = __builtin_amdgcn_mfma_f32_16x16x32_bf16(a1[1], b1, acc1[nt], 0, 0, 0);
        acc2[nt] = __builtin_amdgcn_mfma_f32_16x16x32_bf16(a2[0], b0, z, 0, 0, 0);
        acc2[nt] = __builtin_amdgcn_mfma_f32_16x16x32_bf16(a2[1], b1, acc2[nt], 0, 0, 0);
    }

    const float sA = scale[0], sB = scale1[0];
    #pragma unroll
    for (int nt = 0; nt < 4; ++nt) {
        #pragma unroll
        for (int reg = 0; reg < 4; ++reg) {
            size_t row = (((size_t)(b * Cn + wc + lg * 4 + reg)) << 12)
                         + n0 + nt * 16 + lr;
            out1[row] = sA * acc1[nt][reg] + x1[row];
            out2[row] = sB * acc2[nt][reg] + x2[row];
        }
    }
}

// ---------------------------------------------------------------------------
extern "C" void kernel_launch(void* const* d_in, const int* in_sizes, int n_in,
                              void* d_out, int out_size, void* d_ws, size_t ws_size,
                              hipStream_t stream)
{
    const float* x1     = (const float*)d_in[0];
    const float* y1     = (const float*)d_in[1];
    const float* x2     = (const float*)d_in[2];
    const float* y2     = (const float*)d_in[3];
    const float* wq     = (const float*)d_in[4];
    const float* bq     = (const float*)d_in[5];
    const float* wk     = (const float*)d_in[6];
    const float* bk     = (const float*)d_in[7];
    const float* wv     = (const float*)d_in[8];
    const float* bv     = (const float*)d_in[9];
    const float* scale  = (const float*)d_in[10];
    const float* scale1 = (const float*)d_in[11];

    float* out1 = (float*)d_out;
    float* out2 = out1 + (size_t)Bn * Cn * Nn;

    float* ws    = (float*)d_ws;
    float* wvT   = ws;                     // 262144 f
    float* W2cm  = wvT + 262144;           // 262144 f
    float* m0    = W2cm + 262144;          // 512 f
    float* wbv   = m0 + 512;               // 520 f (513 used)
    float* e0    = wbv + 520;              // 512 f
    u16*   pv1h  = (u16*)(e0 + 512);       // 262144 u16
    u16*   pv2h  = pv1h + 262144;          // 262144 u16
    u16*   Mth   = pv2h + 262144;          // 262144 u16
    u16*   attG  = Mth + 262144;           // 2097152 u16 (4 MB)

    mk_W2_kernel<<<512, 256, 0, stream>>>(wq, wk, bq, bk, W2cm, m0, wbv);
    transpose_wv_kernel<<<64, 256, 0, stream>>>(wv, wvT);
    proj_gemm_kernel<<<dim3(8, 8, 3), 256, 0, stream>>>(
        y1, y2, wvT, W2cm, bv, m0, pv1h, pv2h, Mth);
    e0_kernel<<<Bn, 512, 0, stream>>>(y2, wbv, e0);
    energy_softmax_kernel<<<512, 256, 0, stream>>>(x2, Mth, e0, attG);
    out_kernel<<<dim3(64, 8, 8), 256, 0, stream>>>(
        x1, x2, pv1h, pv2h, attG, scale, scale1, out1, out2);
}

// Round 5
// 168.251 us; speedup vs baseline: 1.1228x; 1.1228x over previous
//
#include <hip/hip_runtime.h>
#include <math.h>

#define Bn 8
#define Cn 512
#define Kn 64
#define C4n 128
#define Nn 4096

typedef short bf16x8 __attribute__((ext_vector_type(8)));
typedef float f32x4  __attribute__((ext_vector_type(4)));
typedef unsigned short u16;

__device__ __forceinline__ u16 f2bf(float f) {
    union { float f; unsigned u; } v; v.f = f;
    unsigned r = v.u + 0x7FFF + ((v.u >> 16) & 1);   // RNE
    return (u16)(r >> 16);
}
__device__ __forceinline__ float bf2f(u16 h) {
    union { unsigned u; float f; } v; v.u = ((unsigned)h) << 16;
    return v.f;
}
// convert 8 consecutive f32 (two float4) to a bf16x8 fragment
__device__ __forceinline__ bf16x8 cvt8(const float* p) {
    float4 a = *(const float4*)p;
    float4 b = *(const float4*)(p + 4);
    bf16x8 r;
    r[0] = (short)f2bf(a.x); r[1] = (short)f2bf(a.y);
    r[2] = (short)f2bf(a.z); r[3] = (short)f2bf(a.w);
    r[4] = (short)f2bf(b.x); r[5] = (short)f2bf(b.y);
    r[6] = (short)f2bf(b.z); r[7] = (short)f2bf(b.w);
    return r;
}

// ---------------------------------------------------------------------------
// kkh[b][k][d] = bf16( sum_c' y2[b,k,c'] * wk[d,c'] + bk[d] )
// Grid: 8 blocks (b), 256 threads. Wave wid -> d range [wid*32, wid*32+32).
__global__ __launch_bounds__(256) void kk_mfma_kernel(
    const float* __restrict__ y2, const float* __restrict__ wk,
    const float* __restrict__ bk, u16* __restrict__ kkh)
{
    const int b    = blockIdx.x;
    const int t    = threadIdx.x;
    const int lane = t & 63;
    const int wid  = t >> 6;
    const int lr   = lane & 15;
    const int lg   = lane >> 4;
    const int d0w  = wid * 32;

    f32x4 acc[2][4];
    #pragma unroll
    for (int dt = 0; dt < 2; ++dt)
        #pragma unroll
        for (int kt = 0; kt < 4; ++kt) acc[dt][kt] = (f32x4){0.f, 0.f, 0.f, 0.f};

    for (int c0 = 0; c0 < Cn; c0 += 32) {
        const int cf = c0 + lg * 8;
        bf16x8 wfr[2], yfr[4];
        #pragma unroll
        for (int dt = 0; dt < 2; ++dt)
            wfr[dt] = cvt8(wk + (size_t)(d0w + dt * 16 + lr) * Cn + cf);
        #pragma unroll
        for (int kt = 0; kt < 4; ++kt)
            yfr[kt] = cvt8(y2 + (size_t)(b * Kn + kt * 16 + lr) * Cn + cf);
        #pragma unroll
        for (int dt = 0; dt < 2; ++dt)
            #pragma unroll
            for (int kt = 0; kt < 4; ++kt)
                acc[dt][kt] = __builtin_amdgcn_mfma_f32_16x16x32_bf16(
                    wfr[dt], yfr[kt], acc[dt][kt], 0, 0, 0);
    }
    // D: col = k (lane&15), rows = d = d0w + dt*16 + 4*lg + reg
    #pragma unroll
    for (int dt = 0; dt < 2; ++dt) {
        const int d4 = d0w + dt * 16 + 4 * lg;
        float4 bkv = *(const float4*)&bk[d4];
        #pragma unroll
        for (int kt = 0; kt < 4; ++kt) {
            ushort4 o;
            o.x = f2bf(acc[dt][kt][0] + bkv.x);
            o.y = f2bf(acc[dt][kt][1] + bkv.y);
            o.z = f2bf(acc[dt][kt][2] + bkv.z);
            o.w = f2bf(acc[dt][kt][3] + bkv.w);
            *(ushort4*)&kkh[(((size_t)(b * Kn + kt * 16 + lr)) << 7) + d4] = o;
        }
    }
}

// ---------------------------------------------------------------------------
// e0[b,k] = sum_d bq[d] * kkh[b][k][d]
__global__ __launch_bounds__(64) void e0_kernel(
    const u16* __restrict__ kkh, const float* __restrict__ bq,
    float* __restrict__ e0)
{
    const int b = blockIdx.x;
    const int k = threadIdx.x;
    const u16* row = kkh + (((size_t)(b * Kn + k)) << 7);
    float acc = 0.f;
    #pragma unroll
    for (int d8 = 0; d8 < C4n; d8 += 8) {
        bf16x8 v = *(const bf16x8*)(row + d8);
        #pragma unroll
        for (int j = 0; j < 8; ++j)
            acc += bq[d8 + j] * bf2f((u16)v[j]);
    }
    e0[b * Kn + k] = acc;
}

// ---------------------------------------------------------------------------
// Mth[b][k][c] = bf16( sum_d kkh[b][k][d] * wq[d,c] )
// Grid: dim3(4 cblk, 8 b), 256 threads. Wave wid -> c range [cblk*128+wid*32).
__global__ __launch_bounds__(256) void M_mfma_kernel(
    const u16* __restrict__ kkh, const float* __restrict__ wq,
    u16* __restrict__ Mth)
{
    const int cb   = blockIdx.x * 128 + (threadIdx.x >> 6) * 32;
    const int b    = blockIdx.y;
    const int lane = threadIdx.x & 63;
    const int lr   = lane & 15;
    const int lg   = lane >> 4;

    f32x4 acc[2][4];
    #pragma unroll
    for (int ct = 0; ct < 2; ++ct)
        #pragma unroll
        for (int kt = 0; kt < 4; ++kt) acc[ct][kt] = (f32x4){0.f, 0.f, 0.f, 0.f};

    for (int d0 = 0; d0 < C4n; d0 += 32) {
        const int df = d0 + lg * 8;
        // A-frag: wqT[c][d] built from scalar wq loads (wq is [d][c])
        bf16x8 afr[2];
        #pragma unroll
        for (int ct = 0; ct < 2; ++ct) {
            const int c = cb + ct * 16 + lr;
            bf16x8 r;
            #pragma unroll
            for (int j = 0; j < 8; ++j)
                r[j] = (short)f2bf(wq[(size_t)(df + j) * Cn + c]);
            afr[ct] = r;
        }
        bf16x8 bfr[4];
        #pragma unroll
        for (int kt = 0; kt < 4; ++kt)
            bfr[kt] = *(const bf16x8*)&kkh[(((size_t)(b * Kn + kt * 16 + lr)) << 7) + df];
        #pragma unroll
        for (int ct = 0; ct < 2; ++ct)
            #pragma unroll
            for (int kt = 0; kt < 4; ++kt)
                acc[ct][kt] = __builtin_amdgcn_mfma_f32_16x16x32_bf16(
                    afr[ct], bfr[kt], acc[ct][kt], 0, 0, 0);
    }
    // D: col = k, rows = c = cb + ct*16 + 4*lg + reg
    #pragma unroll
    for (int ct = 0; ct < 2; ++ct) {
        const int c4 = cb + ct * 16 + 4 * lg;
        #pragma unroll
        for (int kt = 0; kt < 4; ++kt) {
            ushort4 o;
            o.x = f2bf(acc[ct][kt][0]); o.y = f2bf(acc[ct][kt][1]);
            o.z = f2bf(acc[ct][kt][2]); o.w = f2bf(acc[ct][kt][3]);
            *(ushort4*)&Mth[(size_t)(b * Kn + kt * 16 + lr) * Cn + c4] = o;
        }
    }
}

// ---------------------------------------------------------------------------
// pv{sel}h[b][c][k] = bf16( sum_c' y[b,k,c'] * wv[c,c'] + bv[c] )
// Grid: dim3(8 cblk, 8 b, 2 sel), 256 threads. Wave wid -> 16 c.
__global__ __launch_bounds__(256) void pv_mfma_kernel(
    const float* __restrict__ y1, const float* __restrict__ y2,
    const float* __restrict__ wv, const float* __restrict__ bv,
    u16* __restrict__ pv1h, u16* __restrict__ pv2h)
{
    const int cb   = blockIdx.x * 64 + (threadIdx.x >> 6) * 16;
    const int b    = blockIdx.y;
    const int sel  = blockIdx.z;
    const float* y = sel ? y2 : y1;
    u16* pvh       = sel ? pv2h : pv1h;
    const int lane = threadIdx.x & 63;
    const int lr   = lane & 15;
    const int lg   = lane >> 4;

    f32x4 acc[4];
    #pragma unroll
    for (int kt = 0; kt < 4; ++kt) acc[kt] = (f32x4){0.f, 0.f, 0.f, 0.f};

    for (int c0 = 0; c0 < Cn; c0 += 32) {
        const int cf = c0 + lg * 8;
        bf16x8 wfr = cvt8(wv + (size_t)(cb + lr) * Cn + cf);
        bf16x8 yfr[4];
        #pragma unroll
        for (int kt = 0; kt < 4; ++kt)
            yfr[kt] = cvt8(y + (size_t)(b * Kn + kt * 16 + lr) * Cn + cf);
        #pragma unroll
        for (int kt = 0; kt < 4; ++kt)
            acc[kt] = __builtin_amdgcn_mfma_f32_16x16x32_bf16(
                yfr[kt], wfr, acc[kt], 0, 0, 0);
    }
    // D: col = c = cb + lane&15, rows = k = kt*16 + 4*lg + reg
    const int c = cb + lr;
    const float bb = bv[c];
    #pragma unroll
    for (int kt = 0; kt < 4; ++kt) {
        ushort4 o;
        o.x = f2bf(acc[kt][0] + bb); o.y = f2bf(acc[kt][1] + bb);
        o.z = f2bf(acc[kt][2] + bb); o.w = f2bf(acc[kt][3] + bb);
        *(ushort4*)&pvh[(((size_t)(b * Cn + c)) << 6) + kt * 16 + 4 * lg] = o;
    }
}

// ---------------------------------------------------------------------------
// Energy + softmax: attG[b][n][k] = softmax_k |x2ᵀ·M + e0|  (bf16, normalized)
// Grid 512 (b = id&7, 64-n tile = id>>3), 256 threads.  (unchanged)
__global__ __launch_bounds__(256) void energy_softmax_kernel(
    const float* __restrict__ x2, const u16* __restrict__ Mth,
    const float* __restrict__ e0, u16* __restrict__ attG)
{
    __shared__ float Xs[32 * 68];

    const int id   = blockIdx.x;
    const int b    = id & 7;
    const int n0   = (id >> 3) * 64;
    const int t    = threadIdx.x;
    const int lane = t & 63;
    const int wid  = t >> 6;
    const int lr   = lane & 15;
    const int lg   = lane >> 4;
    const int wn0  = wid * 16;

    f32x4 eacc[4];
    #pragma unroll
    for (int kt = 0; kt < 4; ++kt) eacc[kt] = (f32x4){0.f, 0.f, 0.f, 0.f};

    const int sc = t >> 3;
    const int sb = (t & 7) * 8;

    const float* src0 = x2 + (((size_t)(b * Cn + sc)) << 12) + n0 + sb;
    float4 r0 = *(const float4*)src0;
    float4 r1 = *(const float4*)(src0 + 4);

    for (int c0 = 0; c0 < Cn; c0 += 32) {
        __syncthreads();
        *(float4*)&Xs[sc * 68 + sb]     = r0;
        *(float4*)&Xs[sc * 68 + sb + 4] = r1;
        __syncthreads();
        if (c0 + 32 < Cn) {
            const float* src = x2 + (((size_t)(b * Cn + c0 + 32 + sc)) << 12) + n0 + sb;
            r0 = *(const float4*)src;
            r1 = *(const float4*)(src + 4);
        }
        bf16x8 av;
        #pragma unroll
        for (int j = 0; j < 8; ++j)
            av[j] = (short)f2bf(Xs[(lg * 8 + j) * 68 + wn0 + lr]);
        const u16* mb = Mth + ((size_t)b << 15) + (size_t)lr * Cn + c0 + lg * 8;
        #pragma unroll
        for (int kt = 0; kt < 4; ++kt) {
            bf16x8 bv = *(const bf16x8*)(mb + ((size_t)kt << 13));
            eacc[kt] = __builtin_amdgcn_mfma_f32_16x16x32_bf16(av, bv, eacc[kt], 0, 0, 0);
        }
    }

    float e0v[4];
    #pragma unroll
    for (int kt = 0; kt < 4; ++kt) e0v[kt] = e0[b * Kn + lr + 16 * kt];
    #pragma unroll
    for (int reg = 0; reg < 4; ++reg) {
        float a[4];
        #pragma unroll
        for (int kt = 0; kt < 4; ++kt) a[kt] = fabsf(eacc[kt][reg] + e0v[kt]);
        float mx = fmaxf(fmaxf(a[0], a[1]), fmaxf(a[2], a[3]));
        #pragma unroll
        for (int m = 1; m <= 8; m <<= 1) mx = fmaxf(mx, __shfl_xor(mx, m));
        float s = 0.f;
        #pragma unroll
        for (int kt = 0; kt < 4; ++kt) { a[kt] = __expf(a[kt] - mx); s += a[kt]; }
        #pragma unroll
        for (int m = 1; m <= 8; m <<= 1) s += __shfl_xor(s, m);
        float inv = 1.0f / s;
        const int n = n0 + wn0 + lg * 4 + reg;
        u16* dst = attG + (((size_t)b << 18) | ((size_t)n << 6));
        #pragma unroll
        for (int kt = 0; kt < 4; ++kt)
            dst[lr + 16 * kt] = f2bf(a[kt] * inv);
    }
}

// ---------------------------------------------------------------------------
// Streaming out kernel (operand-swapped): lane owns ONE c, 4-consecutive-n
// accumulator regs -> fully float4 epilogue.
// Grid dim3(64 nt, 8 ct, 8 b), 256 threads, no LDS.
__global__ __launch_bounds__(256) void out_kernel(
    const float* __restrict__ x1, const float* __restrict__ x2,
    const u16* __restrict__ pv1h, const u16* __restrict__ pv2h,
    const u16* __restrict__ attG,
    const float* __restrict__ scale, const float* __restrict__ scale1,
    float* __restrict__ out1, float* __restrict__ out2)
{
    const int n0   = blockIdx.x * 64;
    const int ct   = blockIdx.y;
    const int b    = blockIdx.z;
    const int t    = threadIdx.x;
    const int lane = t & 63;
    const int wid  = t >> 6;
    const int lr   = lane & 15;
    const int lg   = lane >> 4;
    const int wc   = ct * 64 + wid * 16;

    // B-frags: pv[b][c = wc+lr][k], k-chunks at lg*8 and 32+lg*8
    const u16* p1 = pv1h + (((size_t)(b * Cn + wc + lr)) << 6) + lg * 8;
    const u16* p2 = pv2h + (((size_t)(b * Cn + wc + lr)) << 6) + lg * 8;
    bf16x8 v1[2], v2[2];
    v1[0] = *(const bf16x8*)p1;  v1[1] = *(const bf16x8*)(p1 + 32);
    v2[0] = *(const bf16x8*)p2;  v2[1] = *(const bf16x8*)(p2 + 32);

    // A-frags: att[b][n = n0+nt*16+lr][k]; acc rows = n (4 consecutive per lane)
    f32x4 acc1[4], acc2[4];
    #pragma unroll
    for (int nt = 0; nt < 4; ++nt) {
        const u16* ab = attG + (((size_t)b << 18) | ((size_t)(n0 + nt * 16 + lr) << 6)) + lg * 8;
        bf16x8 a0 = *(const bf16x8*)ab;
        bf16x8 a1 = *(const bf16x8*)(ab + 32);
        f32x4 z = (f32x4){0.f, 0.f, 0.f, 0.f};
        acc1[nt] = __builtin_amdgcn_mfma_f32_16x16x32_bf16(a0, v1[0], z, 0, 0, 0);
        acc1[nt] = __builtin_amdgcn_mfma_f32_16x16x32_bf16(a1, v1[1], acc1[nt], 0, 0, 0);
        acc2[nt] = __builtin_amdgcn_mfma_f32_16x16x32_bf16(a0, v2[0], z, 0, 0, 0);
        acc2[nt] = __builtin_amdgcn_mfma_f32_16x16x32_bf16(a1, v2[1], acc2[nt], 0, 0, 0);
    }

    const float sA = scale[0], sB = scale1[0];
    // lane: c = wc+lr, n = n0 + nt*16 + 4*lg + reg  -> float4 along n
    const size_t rowbase = (((size_t)(b * Cn + wc + lr)) << 12) + n0 + 4 * lg;
    #pragma unroll
    for (int nt = 0; nt < 4; ++nt) {
        const size_t row = rowbase + nt * 16;
        float4 xv1 = *(const float4*)&x1[row];
        float4 xv2 = *(const float4*)&x2[row];
        float4 o1, o2;
        o1.x = sA * acc1[nt][0] + xv1.x;  o1.y = sA * acc1[nt][1] + xv1.y;
        o1.z = sA * acc1[nt][2] + xv1.z;  o1.w = sA * acc1[nt][3] + xv1.w;
        o2.x = sB * acc2[nt][0] + xv2.x;  o2.y = sB * acc2[nt][1] + xv2.y;
        o2.z = sB * acc2[nt][2] + xv2.z;  o2.w = sB * acc2[nt][3] + xv2.w;
        *(float4*)&out1[row] = o1;
        *(float4*)&out2[row] = o2;
    }
}

// ---------------------------------------------------------------------------
extern "C" void kernel_launch(void* const* d_in, const int* in_sizes, int n_in,
                              void* d_out, int out_size, void* d_ws, size_t ws_size,
                              hipStream_t stream)
{
    const float* x1     = (const float*)d_in[0];
    const float* y1     = (const float*)d_in[1];
    const float* x2     = (const float*)d_in[2];
    const float* y2     = (const float*)d_in[3];
    const float* wq     = (const float*)d_in[4];
    const float* bq     = (const float*)d_in[5];
    const float* wk     = (const float*)d_in[6];
    const float* bk     = (const float*)d_in[7];
    const float* wv     = (const float*)d_in[8];
    const float* bv     = (const float*)d_in[9];
    const float* scale  = (const float*)d_in[10];
    const float* scale1 = (const float*)d_in[11];

    float* out1 = (float*)d_out;
    float* out2 = out1 + (size_t)Bn * Cn * Nn;

    float* ws   = (float*)d_ws;
    float* e0   = ws;                       // 512 f
    u16*   kkh  = (u16*)(ws + 512);         // 65536 u16
    u16*   Mth  = kkh + 65536;              // 262144 u16
    u16*   pv1h = Mth + 262144;             // 262144 u16
    u16*   pv2h = pv1h + 262144;            // 262144 u16
    u16*   attG = pv2h + 262144;            // 2097152 u16

    kk_mfma_kernel<<<Bn, 256, 0, stream>>>(y2, wk, bk, kkh);
    e0_kernel<<<Bn, 64, 0, stream>>>(kkh, bq, e0);
    M_mfma_kernel<<<dim3(4, Bn), 256, 0, stream>>>(kkh, wq, Mth);
    pv_mfma_kernel<<<dim3(8, Bn, 2), 256, 0, stream>>>(y1, y2, wv, bv, pv1h, pv2h);
    energy_softmax_kernel<<<512, 256, 0, stream>>>(x2, Mth, e0, attG);
    out_kernel<<<dim3(64, 8, 8), 256, 0, stream>>>(
        x1, x2, pv1h, pv2h, attG, scale, scale1, out1, out2);
}

// Round 6
// 130.351 us; speedup vs baseline: 1.4492x; 1.2908x over previous
//
#include <hip/hip_runtime.h>
#include <math.h>

#define Bn 8
#define Cn 512
#define Kn 64
#define C4n 128
#define Nn 4096

typedef short bf16x8 __attribute__((ext_vector_type(8)));
typedef float f32x4  __attribute__((ext_vector_type(4)));
typedef unsigned short u16;

__device__ __forceinline__ u16 f2bf(float f) {
    union { float f; unsigned u; } v; v.f = f;
    unsigned r = v.u + 0x7FFF + ((v.u >> 16) & 1);   // RNE
    return (u16)(r >> 16);
}
__device__ __forceinline__ float bf2f(u16 h) {
    union { unsigned u; float f; } v; v.u = ((unsigned)h) << 16;
    return v.f;
}
// convert 8 consecutive f32 (two float4) to a bf16x8 fragment
__device__ __forceinline__ bf16x8 cvt8(const float* p) {
    float4 a = *(const float4*)p;
    float4 b = *(const float4*)(p + 4);
    bf16x8 r;
    r[0] = (short)f2bf(a.x); r[1] = (short)f2bf(a.y);
    r[2] = (short)f2bf(a.z); r[3] = (short)f2bf(a.w);
    r[4] = (short)f2bf(b.x); r[5] = (short)f2bf(b.y);
    r[6] = (short)f2bf(b.z); r[7] = (short)f2bf(b.w);
    return r;
}

// ---------------------------------------------------------------------------
// kkh[b][k][d] = bf16( sum_c' y2[b,k,c'] * wk[d,c'] + bk[d] )
__global__ __launch_bounds__(256) void kk_mfma_kernel(
    const float* __restrict__ y2, const float* __restrict__ wk,
    const float* __restrict__ bk, u16* __restrict__ kkh)
{
    const int b    = blockIdx.x;
    const int t    = threadIdx.x;
    const int lane = t & 63;
    const int wid  = t >> 6;
    const int lr   = lane & 15;
    const int lg   = lane >> 4;
    const int d0w  = wid * 32;

    f32x4 acc[2][4];
    #pragma unroll
    for (int dt = 0; dt < 2; ++dt)
        #pragma unroll
        for (int kt = 0; kt < 4; ++kt) acc[dt][kt] = (f32x4){0.f, 0.f, 0.f, 0.f};

    for (int c0 = 0; c0 < Cn; c0 += 32) {
        const int cf = c0 + lg * 8;
        bf16x8 wfr[2], yfr[4];
        #pragma unroll
        for (int dt = 0; dt < 2; ++dt)
            wfr[dt] = cvt8(wk + (size_t)(d0w + dt * 16 + lr) * Cn + cf);
        #pragma unroll
        for (int kt = 0; kt < 4; ++kt)
            yfr[kt] = cvt8(y2 + (size_t)(b * Kn + kt * 16 + lr) * Cn + cf);
        #pragma unroll
        for (int dt = 0; dt < 2; ++dt)
            #pragma unroll
            for (int kt = 0; kt < 4; ++kt)
                acc[dt][kt] = __builtin_amdgcn_mfma_f32_16x16x32_bf16(
                    wfr[dt], yfr[kt], acc[dt][kt], 0, 0, 0);
    }
    #pragma unroll
    for (int dt = 0; dt < 2; ++dt) {
        const int d4 = d0w + dt * 16 + 4 * lg;
        float4 bkv = *(const float4*)&bk[d4];
        #pragma unroll
        for (int kt = 0; kt < 4; ++kt) {
            ushort4 o;
            o.x = f2bf(acc[dt][kt][0] + bkv.x);
            o.y = f2bf(acc[dt][kt][1] + bkv.y);
            o.z = f2bf(acc[dt][kt][2] + bkv.z);
            o.w = f2bf(acc[dt][kt][3] + bkv.w);
            *(ushort4*)&kkh[(((size_t)(b * Kn + kt * 16 + lr)) << 7) + d4] = o;
        }
    }
}

// ---------------------------------------------------------------------------
// e0[b,k] = sum_d bq[d] * kkh[b][k][d]
__global__ __launch_bounds__(64) void e0_kernel(
    const u16* __restrict__ kkh, const float* __restrict__ bq,
    float* __restrict__ e0)
{
    const int b = blockIdx.x;
    const int k = threadIdx.x;
    const u16* row = kkh + (((size_t)(b * Kn + k)) << 7);
    float acc = 0.f;
    #pragma unroll
    for (int d8 = 0; d8 < C4n; d8 += 8) {
        bf16x8 v = *(const bf16x8*)(row + d8);
        #pragma unroll
        for (int j = 0; j < 8; ++j)
            acc += bq[d8 + j] * bf2f((u16)v[j]);
    }
    e0[b * Kn + k] = acc;
}

// ---------------------------------------------------------------------------
// Mth[b][k][c] = bf16( sum_d kkh[b][k][d] * wq[d,c] )
__global__ __launch_bounds__(256) void M_mfma_kernel(
    const u16* __restrict__ kkh, const float* __restrict__ wq,
    u16* __restrict__ Mth)
{
    const int cb   = blockIdx.x * 128 + (threadIdx.x >> 6) * 32;
    const int b    = blockIdx.y;
    const int lane = threadIdx.x & 63;
    const int lr   = lane & 15;
    const int lg   = lane >> 4;

    f32x4 acc[2][4];
    #pragma unroll
    for (int ct = 0; ct < 2; ++ct)
        #pragma unroll
        for (int kt = 0; kt < 4; ++kt) acc[ct][kt] = (f32x4){0.f, 0.f, 0.f, 0.f};

    for (int d0 = 0; d0 < C4n; d0 += 32) {
        const int df = d0 + lg * 8;
        bf16x8 afr[2];
        #pragma unroll
        for (int ct = 0; ct < 2; ++ct) {
            const int c = cb + ct * 16 + lr;
            bf16x8 r;
            #pragma unroll
            for (int j = 0; j < 8; ++j)
                r[j] = (short)f2bf(wq[(size_t)(df + j) * Cn + c]);
            afr[ct] = r;
        }
        bf16x8 bfr[4];
        #pragma unroll
        for (int kt = 0; kt < 4; ++kt)
            bfr[kt] = *(const bf16x8*)&kkh[(((size_t)(b * Kn + kt * 16 + lr)) << 7) + df];
        #pragma unroll
        for (int ct = 0; ct < 2; ++ct)
            #pragma unroll
            for (int kt = 0; kt < 4; ++kt)
                acc[ct][kt] = __builtin_amdgcn_mfma_f32_16x16x32_bf16(
                    afr[ct], bfr[kt], acc[ct][kt], 0, 0, 0);
    }
    #pragma unroll
    for (int ct = 0; ct < 2; ++ct) {
        const int c4 = cb + ct * 16 + 4 * lg;
        #pragma unroll
        for (int kt = 0; kt < 4; ++kt) {
            ushort4 o;
            o.x = f2bf(acc[ct][kt][0]); o.y = f2bf(acc[ct][kt][1]);
            o.z = f2bf(acc[ct][kt][2]); o.w = f2bf(acc[ct][kt][3]);
            *(ushort4*)&Mth[(size_t)(b * Kn + kt * 16 + lr) * Cn + c4] = o;
        }
    }
}

// ---------------------------------------------------------------------------
// pv{sel}h[b][c][k] = bf16( sum_c' y[b,k,c'] * wv[c,c'] + bv[c] )
__global__ __launch_bounds__(256) void pv_mfma_kernel(
    const float* __restrict__ y1, const float* __restrict__ y2,
    const float* __restrict__ wv, const float* __restrict__ bv,
    u16* __restrict__ pv1h, u16* __restrict__ pv2h)
{
    const int cb   = blockIdx.x * 64 + (threadIdx.x >> 6) * 16;
    const int b    = blockIdx.y;
    const int sel  = blockIdx.z;
    const float* y = sel ? y2 : y1;
    u16* pvh       = sel ? pv2h : pv1h;
    const int lane = threadIdx.x & 63;
    const int lr   = lane & 15;
    const int lg   = lane >> 4;

    f32x4 acc[4];
    #pragma unroll
    for (int kt = 0; kt < 4; ++kt) acc[kt] = (f32x4){0.f, 0.f, 0.f, 0.f};

    for (int c0 = 0; c0 < Cn; c0 += 32) {
        const int cf = c0 + lg * 8;
        bf16x8 wfr = cvt8(wv + (size_t)(cb + lr) * Cn + cf);
        bf16x8 yfr[4];
        #pragma unroll
        for (int kt = 0; kt < 4; ++kt)
            yfr[kt] = cvt8(y + (size_t)(b * Kn + kt * 16 + lr) * Cn + cf);
        #pragma unroll
        for (int kt = 0; kt < 4; ++kt)
            acc[kt] = __builtin_amdgcn_mfma_f32_16x16x32_bf16(
                yfr[kt], wfr, acc[kt], 0, 0, 0);
    }
    const int c = cb + lr;
    const float bb = bv[c];
    #pragma unroll
    for (int kt = 0; kt < 4; ++kt) {
        ushort4 o;
        o.x = f2bf(acc[kt][0] + bb); o.y = f2bf(acc[kt][1] + bb);
        o.z = f2bf(acc[kt][2] + bb); o.w = f2bf(acc[kt][3] + bb);
        *(ushort4*)&pvh[(((size_t)(b * Cn + c)) << 6) + kt * 16 + 4 * lg] = o;
    }
}

// ---------------------------------------------------------------------------
// Energy + softmax: attG[b][n][k] = softmax_k |x2ᵀ·M + e0|  (bf16, normalized)
// Grid 512 (b = id&7, 64-n tile = id>>3), 256 threads.  (unchanged)
__global__ __launch_bounds__(256) void energy_softmax_kernel(
    const float* __restrict__ x2, const u16* __restrict__ Mth,
    const float* __restrict__ e0, u16* __restrict__ attG)
{
    __shared__ float Xs[32 * 68];

    const int id   = blockIdx.x;
    const int b    = id & 7;
    const int n0   = (id >> 3) * 64;
    const int t    = threadIdx.x;
    const int lane = t & 63;
    const int wid  = t >> 6;
    const int lr   = lane & 15;
    const int lg   = lane >> 4;
    const int wn0  = wid * 16;

    f32x4 eacc[4];
    #pragma unroll
    for (int kt = 0; kt < 4; ++kt) eacc[kt] = (f32x4){0.f, 0.f, 0.f, 0.f};

    const int sc = t >> 3;
    const int sb = (t & 7) * 8;

    const float* src0 = x2 + (((size_t)(b * Cn + sc)) << 12) + n0 + sb;
    float4 r0 = *(const float4*)src0;
    float4 r1 = *(const float4*)(src0 + 4);

    for (int c0 = 0; c0 < Cn; c0 += 32) {
        __syncthreads();
        *(float4*)&Xs[sc * 68 + sb]     = r0;
        *(float4*)&Xs[sc * 68 + sb + 4] = r1;
        __syncthreads();
        if (c0 + 32 < Cn) {
            const float* src = x2 + (((size_t)(b * Cn + c0 + 32 + sc)) << 12) + n0 + sb;
            r0 = *(const float4*)src;
            r1 = *(const float4*)(src + 4);
        }
        bf16x8 av;
        #pragma unroll
        for (int j = 0; j < 8; ++j)
            av[j] = (short)f2bf(Xs[(lg * 8 + j) * 68 + wn0 + lr]);
        const u16* mb = Mth + ((size_t)b << 15) + (size_t)lr * Cn + c0 + lg * 8;
        #pragma unroll
        for (int kt = 0; kt < 4; ++kt) {
            bf16x8 bv = *(const bf16x8*)(mb + ((size_t)kt << 13));
            eacc[kt] = __builtin_amdgcn_mfma_f32_16x16x32_bf16(av, bv, eacc[kt], 0, 0, 0);
        }
    }

    float e0v[4];
    #pragma unroll
    for (int kt = 0; kt < 4; ++kt) e0v[kt] = e0[b * Kn + lr + 16 * kt];
    #pragma unroll
    for (int reg = 0; reg < 4; ++reg) {
        float a[4];
        #pragma unroll
        for (int kt = 0; kt < 4; ++kt) a[kt] = fabsf(eacc[kt][reg] + e0v[kt]);
        float mx = fmaxf(fmaxf(a[0], a[1]), fmaxf(a[2], a[3]));
        #pragma unroll
        for (int m = 1; m <= 8; m <<= 1) mx = fmaxf(mx, __shfl_xor(mx, m));
        float s = 0.f;
        #pragma unroll
        for (int kt = 0; kt < 4; ++kt) { a[kt] = __expf(a[kt] - mx); s += a[kt]; }
        #pragma unroll
        for (int m = 1; m <= 8; m <<= 1) s += __shfl_xor(s, m);
        float inv = 1.0f / s;
        const int n = n0 + wn0 + lg * 4 + reg;
        u16* dst = attG + (((size_t)b << 18) | ((size_t)n << 6));
        #pragma unroll
        for (int kt = 0; kt < 4; ++kt)
            dst[lr + 16 * kt] = f2bf(a[kt] * inv);
    }
}

// ---------------------------------------------------------------------------
// Streaming out kernel with LDS-relaid, fully line-coalesced epilogue.
// Grid dim3(64 ntile, 4 cpair, 8 b), 256 threads (4 waves), 17 KB LDS.
// Each block: 128 c (2 ct of 64) x 64 n for both outputs.
__global__ __launch_bounds__(256) void out_kernel(
    const float* __restrict__ x1, const float* __restrict__ x2,
    const u16* __restrict__ pv1h, const u16* __restrict__ pv2h,
    const u16* __restrict__ attG,
    const float* __restrict__ scale, const float* __restrict__ scale1,
    float* __restrict__ out1, float* __restrict__ out2)
{
    __shared__ float T[64 * 68];

    const int n0   = blockIdx.x * 64;
    const int cB   = blockIdx.y * 128;
    const int b    = blockIdx.z;
    const int t    = threadIdx.x;
    const int lane = t & 63;
    const int wid  = t >> 6;
    const int lr   = lane & 15;
    const int lg   = lane >> 4;

    // att A-frags, loaded once and reused for both ct and both outputs
    bf16x8 af[4][2];
    #pragma unroll
    for (int nt = 0; nt < 4; ++nt) {
        const u16* ab = attG + (((size_t)b << 18) | ((size_t)(n0 + nt * 16 + lr) << 6)) + lg * 8;
        af[nt][0] = *(const bf16x8*)ab;
        af[nt][1] = *(const bf16x8*)(ab + 32);
    }

    const float sA = scale[0], sB = scale1[0];
    // epilogue thread mapping: row = pass*16 + (t>>4), n-chunk = (t&15)*4
    const int er  = t >> 4;          // 0..15
    const int ech = (t & 15) * 4;    // 0..60

    for (int ct = 0; ct < 2; ++ct) {
        const int wc = cB + ct * 64 + wid * 16;

        // pv B-frags
        const u16* p1 = pv1h + (((size_t)(b * Cn + wc + lr)) << 6) + lg * 8;
        const u16* p2 = pv2h + (((size_t)(b * Cn + wc + lr)) << 6) + lg * 8;
        bf16x8 v1[2], v2[2];
        v1[0] = *(const bf16x8*)p1;  v1[1] = *(const bf16x8*)(p1 + 32);
        v2[0] = *(const bf16x8*)p2;  v2[1] = *(const bf16x8*)(p2 + 32);

        f32x4 acc1[4], acc2[4];
        #pragma unroll
        for (int nt = 0; nt < 4; ++nt) {
            f32x4 z = (f32x4){0.f, 0.f, 0.f, 0.f};
            acc1[nt] = __builtin_amdgcn_mfma_f32_16x16x32_bf16(af[nt][0], v1[0], z, 0, 0, 0);
            acc1[nt] = __builtin_amdgcn_mfma_f32_16x16x32_bf16(af[nt][1], v1[1], acc1[nt], 0, 0, 0);
            acc2[nt] = __builtin_amdgcn_mfma_f32_16x16x32_bf16(af[nt][0], v2[0], z, 0, 0, 0);
            acc2[nt] = __builtin_amdgcn_mfma_f32_16x16x32_bf16(af[nt][1], v2[1], acc2[nt], 0, 0, 0);
        }

        // ---- output 1: stage -> coalesced drain ----
        __syncthreads();
        #pragma unroll
        for (int nt = 0; nt < 4; ++nt) {
            float4 v;
            v.x = acc1[nt][0]; v.y = acc1[nt][1];
            v.z = acc1[nt][2]; v.w = acc1[nt][3];
            *(float4*)&T[(wid * 16 + lr) * 68 + nt * 16 + 4 * lg] = v;
        }
        __syncthreads();
        #pragma unroll
        for (int pass = 0; pass < 4; ++pass) {
            const int rl = pass * 16 + er;
            const size_t row = (((size_t)(b * Cn + cB + ct * 64 + rl)) << 12) + n0 + ech;
            float4 a = *(const float4*)&T[rl * 68 + ech];
            float4 xv = *(const float4*)&x1[row];
            float4 o;
            o.x = sA * a.x + xv.x;  o.y = sA * a.y + xv.y;
            o.z = sA * a.z + xv.z;  o.w = sA * a.w + xv.w;
            *(float4*)&out1[row] = o;
        }

        // ---- output 2: stage -> coalesced drain ----
        __syncthreads();
        #pragma unroll
        for (int nt = 0; nt < 4; ++nt) {
            float4 v;
            v.x = acc2[nt][0]; v.y = acc2[nt][1];
            v.z = acc2[nt][2]; v.w = acc2[nt][3];
            *(float4*)&T[(wid * 16 + lr) * 68 + nt * 16 + 4 * lg] = v;
        }
        __syncthreads();
        #pragma unroll
        for (int pass = 0; pass < 4; ++pass) {
            const int rl = pass * 16 + er;
            const size_t row = (((size_t)(b * Cn + cB + ct * 64 + rl)) << 12) + n0 + ech;
            float4 a = *(const float4*)&T[rl * 68 + ech];
            float4 xv = *(const float4*)&x2[row];
            float4 o;
            o.x = sB * a.x + xv.x;  o.y = sB * a.y + xv.y;
            o.z = sB * a.z + xv.z;  o.w = sB * a.w + xv.w;
            *(float4*)&out2[row] = o;
        }
    }
}

// ---------------------------------------------------------------------------
extern "C" void kernel_launch(void* const* d_in, const int* in_sizes, int n_in,
                              void* d_out, int out_size, void* d_ws, size_t ws_size,
                              hipStream_t stream)
{
    const float* x1     = (const float*)d_in[0];
    const float* y1     = (const float*)d_in[1];
    const float* x2     = (const float*)d_in[2];
    const float* y2     = (const float*)d_in[3];
    const float* wq     = (const float*)d_in[4];
    const float* bq     = (const float*)d_in[5];
    const float* wk     = (const float*)d_in[6];
    const float* bk     = (const float*)d_in[7];
    const float* wv     = (const float*)d_in[8];
    const float* bv     = (const float*)d_in[9];
    const float* scale  = (const float*)d_in[10];
    const float* scale1 = (const float*)d_in[11];

    float* out1 = (float*)d_out;
    float* out2 = out1 + (size_t)Bn * Cn * Nn;

    float* ws   = (float*)d_ws;
    float* e0   = ws;                       // 512 f
    u16*   kkh  = (u16*)(ws + 512);         // 65536 u16
    u16*   Mth  = kkh + 65536;              // 262144 u16
    u16*   pv1h = Mth + 262144;             // 262144 u16
    u16*   pv2h = pv1h + 262144;            // 262144 u16
    u16*   attG = pv2h + 262144;            // 2097152 u16

    kk_mfma_kernel<<<Bn, 256, 0, stream>>>(y2, wk, bk, kkh);
    e0_kernel<<<Bn, 64, 0, stream>>>(kkh, bq, e0);
    M_mfma_kernel<<<dim3(4, Bn), 256, 0, stream>>>(kkh, wq, Mth);
    pv_mfma_kernel<<<dim3(8, Bn, 2), 256, 0, stream>>>(y1, y2, wv, bv, pv1h, pv2h);
    energy_softmax_kernel<<<512, 256, 0, stream>>>(x2, Mth, e0, attG);
    out_kernel<<<dim3(64, 4, 8), 256, 0, stream>>>(
        x1, x2, pv1h, pv2h, attG, scale, scale1, out1, out2);
}

// Round 8
// 92.546 us; speedup vs baseline: 2.0412x; 1.4085x over previous
//
#include <hip/hip_runtime.h>
#include <math.h>

#define Bn 8
#define Cn 512
#define Kn 64
#define C4n 128
#define Nn 4096

typedef short bf16x8 __attribute__((ext_vector_type(8)));
typedef float f32x4  __attribute__((ext_vector_type(4)));
typedef unsigned short u16;

__device__ __forceinline__ u16 f2bf(float f) {
    union { float f; unsigned u; } v; v.f = f;
    unsigned r = v.u + 0x7FFF + ((v.u >> 16) & 1);   // RNE
    return (u16)(r >> 16);
}
__device__ __forceinline__ float bf2f(u16 h) {
    union { unsigned u; float f; } v; v.u = ((unsigned)h) << 16;
    return v.f;
}
__device__ __forceinline__ bf16x8 cvt8(const float* p) {
    float4 a = *(const float4*)p;
    float4 b = *(const float4*)(p + 4);
    bf16x8 r;
    r[0] = (short)f2bf(a.x); r[1] = (short)f2bf(a.y);
    r[2] = (short)f2bf(a.z); r[3] = (short)f2bf(a.w);
    r[4] = (short)f2bf(b.x); r[5] = (short)f2bf(b.y);
    r[6] = (short)f2bf(b.z); r[7] = (short)f2bf(b.w);
    return r;
}

// ---------------------------------------------------------------------------
// Merged: z<2 -> pv{z}h[b][c][k] = bf16(sum_c' y{z}[b,k,c']*wv[c,c'] + bv[c])
//         z==2 -> kkh[b][k][d]   = bf16(sum_c' y2[b,k,c']*wk[d,c'] + bk[d])
// Grid dim3(8, 8, 3), 256 threads.
__global__ __launch_bounds__(256) void kk_pv_kernel(
    const float* __restrict__ y1, const float* __restrict__ y2,
    const float* __restrict__ wv, const float* __restrict__ bv,
    const float* __restrict__ wk, const float* __restrict__ bk,
    u16* __restrict__ pv1h, u16* __restrict__ pv2h, u16* __restrict__ kkh)
{
    const int b    = blockIdx.y;
    const int sel  = blockIdx.z;
    const int lane = threadIdx.x & 63;
    const int wid  = threadIdx.x >> 6;
    const int lr   = lane & 15;
    const int lg   = lane >> 4;

    if (sel < 2) {
        // ---- pv ----
        const int cb   = blockIdx.x * 64 + wid * 16;
        const float* y = sel ? y2 : y1;
        u16* pvh       = sel ? pv2h : pv1h;

        f32x4 acc[4];
        #pragma unroll
        for (int kt = 0; kt < 4; ++kt) acc[kt] = (f32x4){0.f, 0.f, 0.f, 0.f};

        for (int c0 = 0; c0 < Cn; c0 += 32) {
            const int cf = c0 + lg * 8;
            bf16x8 wfr = cvt8(wv + (size_t)(cb + lr) * Cn + cf);
            bf16x8 yfr[4];
            #pragma unroll
            for (int kt = 0; kt < 4; ++kt)
                yfr[kt] = cvt8(y + (size_t)(b * Kn + kt * 16 + lr) * Cn + cf);
            #pragma unroll
            for (int kt = 0; kt < 4; ++kt)
                acc[kt] = __builtin_amdgcn_mfma_f32_16x16x32_bf16(
                    yfr[kt], wfr, acc[kt], 0, 0, 0);
        }
        const int c = cb + lr;
        const float bb = bv[c];
        #pragma unroll
        for (int kt = 0; kt < 4; ++kt) {
            ushort4 o;
            o.x = f2bf(acc[kt][0] + bb); o.y = f2bf(acc[kt][1] + bb);
            o.z = f2bf(acc[kt][2] + bb); o.w = f2bf(acc[kt][3] + bb);
            *(ushort4*)&pvh[(((size_t)(b * Cn + c)) << 6) + kt * 16 + 4 * lg] = o;
        }
    } else {
        // ---- kk ---- wave wid = kt tile; block x = d tile (16 d)
        const int dblk = blockIdx.x * 16;
        f32x4 acc = (f32x4){0.f, 0.f, 0.f, 0.f};
        for (int c0 = 0; c0 < Cn; c0 += 32) {
            const int cf = c0 + lg * 8;
            bf16x8 wfr = cvt8(wk + (size_t)(dblk + lr) * Cn + cf);
            bf16x8 yfr = cvt8(y2 + (size_t)(b * Kn + wid * 16 + lr) * Cn + cf);
            acc = __builtin_amdgcn_mfma_f32_16x16x32_bf16(wfr, yfr, acc, 0, 0, 0);
        }
        // D: col = k = wid*16+lr, rows = d = dblk + 4*lg + reg
        const int d4 = dblk + 4 * lg;
        float4 bkv = *(const float4*)&bk[d4];
        ushort4 o;
        o.x = f2bf(acc[0] + bkv.x); o.y = f2bf(acc[1] + bkv.y);
        o.z = f2bf(acc[2] + bkv.z); o.w = f2bf(acc[3] + bkv.w);
        *(ushort4*)&kkh[(((size_t)(b * Kn + wid * 16 + lr)) << 7) + d4] = o;
    }
}

// ---------------------------------------------------------------------------
// Merged: x<4 -> Mth[b][k][c] = bf16(sum_d kkh[b][k][d]*wq[d,c])
//         x==4 -> e0[b,k] = sum_d bq[d]*kkh[b][k][d]
// Grid dim3(5, 8), 256 threads.
__global__ __launch_bounds__(256) void M_e0_kernel(
    const u16* __restrict__ kkh, const float* __restrict__ wq,
    const float* __restrict__ bq, u16* __restrict__ Mth,
    float* __restrict__ e0)
{
    const int b = blockIdx.y;
    const int t = threadIdx.x;

    if (blockIdx.x == 4) {
        if (t < Kn) {
            const u16* row = kkh + (((size_t)(b * Kn + t)) << 7);
            float acc = 0.f;
            #pragma unroll
            for (int d8 = 0; d8 < C4n; d8 += 8) {
                bf16x8 v = *(const bf16x8*)(row + d8);
                #pragma unroll
                for (int j = 0; j < 8; ++j)
                    acc += bq[d8 + j] * bf2f((u16)v[j]);
            }
            e0[b * Kn + t] = acc;
        }
        return;
    }

    const int cb   = blockIdx.x * 128 + (t >> 6) * 32;
    const int lane = t & 63;
    const int lr   = lane & 15;
    const int lg   = lane >> 4;

    f32x4 acc[2][4];
    #pragma unroll
    for (int ct = 0; ct < 2; ++ct)
        #pragma unroll
        for (int kt = 0; kt < 4; ++kt) acc[ct][kt] = (f32x4){0.f, 0.f, 0.f, 0.f};

    for (int d0 = 0; d0 < C4n; d0 += 32) {
        const int df = d0 + lg * 8;
        bf16x8 afr[2];
        #pragma unroll
        for (int ct = 0; ct < 2; ++ct) {
            const int c = cb + ct * 16 + lr;
            bf16x8 r;
            #pragma unroll
            for (int j = 0; j < 8; ++j)
                r[j] = (short)f2bf(wq[(size_t)(df + j) * Cn + c]);
            afr[ct] = r;
        }
        bf16x8 bfr[4];
        #pragma unroll
        for (int kt = 0; kt < 4; ++kt)
            bfr[kt] = *(const bf16x8*)&kkh[(((size_t)(b * Kn + kt * 16 + lr)) << 7) + df];
        #pragma unroll
        for (int ct = 0; ct < 2; ++ct)
            #pragma unroll
            for (int kt = 0; kt < 4; ++kt)
                acc[ct][kt] = __builtin_amdgcn_mfma_f32_16x16x32_bf16(
                    afr[ct], bfr[kt], acc[ct][kt], 0, 0, 0);
    }
    #pragma unroll
    for (int ct = 0; ct < 2; ++ct) {
        const int c4 = cb + ct * 16 + 4 * lg;
        #pragma unroll
        for (int kt = 0; kt < 4; ++kt) {
            ushort4 o;
            o.x = f2bf(acc[ct][kt][0]); o.y = f2bf(acc[ct][kt][1]);
            o.z = f2bf(acc[ct][kt][2]); o.w = f2bf(acc[ct][kt][3]);
            *(ushort4*)&Mth[(size_t)(b * Kn + kt * 16 + lr) * Cn + c4] = o;
        }
    }
}

// ---------------------------------------------------------------------------
// Energy + softmax v2: NO LDS, NO barriers. Operand-swapped MFMA:
// D[k][n] = mfma(Mfrag(k,c), x2frag(c,n)). Lane owns one n column, 16 k vals.
// attG[b][n][k] = softmax_k |energy + e0|  (bf16, normalized).
// Grid 512 (b = id&7, 64-n tile = id>>3), 256 threads.
__global__ __launch_bounds__(256) void energy_softmax_kernel(
    const float* __restrict__ x2, const u16* __restrict__ Mth,
    const float* __restrict__ e0, u16* __restrict__ attG)
{
    const int id   = blockIdx.x;
    const int b    = id & 7;
    const int n0   = (id >> 3) * 64;
    const int t    = threadIdx.x;
    const int lane = t & 63;
    const int wid  = t >> 6;
    const int lr   = lane & 15;
    const int lg   = lane >> 4;
    const int n    = n0 + wid * 16 + lr;     // this lane's n column

    f32x4 eacc[4];
    #pragma unroll
    for (int kt = 0; kt < 4; ++kt) eacc[kt] = (f32x4){0.f, 0.f, 0.f, 0.f};

    const float* xcol = x2 + (((size_t)b * Cn) << 12) + n;   // x2[b][c][n]
    const u16*   mb   = Mth + ((size_t)b << 15) + (size_t)lr * Cn;

    for (int c0 = 0; c0 < Cn; c0 += 32) {
        const int cf = c0 + lg * 8;
        // B-frag: x2[cf+j][n], 8 strided scalar loads
        float xs[8];
        #pragma unroll
        for (int j = 0; j < 8; ++j)
            xs[j] = xcol[((size_t)(cf + j)) << 12];
        bf16x8 xfr;
        #pragma unroll
        for (int j = 0; j < 8; ++j) xfr[j] = (short)f2bf(xs[j]);
        // A-frags: Mth[b][kt*16+lr][cf..cf+7], contiguous 16B
        #pragma unroll
        for (int kt = 0; kt < 4; ++kt) {
            bf16x8 av = *(const bf16x8*)(mb + ((size_t)kt << 13) + cf);
            eacc[kt] = __builtin_amdgcn_mfma_f32_16x16x32_bf16(av, xfr, eacc[kt], 0, 0, 0);
        }
    }

    // lane's k set: k = kt*16 + lg*4 + reg. Reduce over 16 local + xor 16,32.
    float a[4][4];
    float mx = 0.f;   // |.| >= 0
    #pragma unroll
    for (int kt = 0; kt < 4; ++kt) {
        float4 e0v = *(const float4*)&e0[b * Kn + kt * 16 + lg * 4];
        float er[4] = {e0v.x, e0v.y, e0v.z, e0v.w};
        #pragma unroll
        for (int reg = 0; reg < 4; ++reg) {
            float v = fabsf(eacc[kt][reg] + er[reg]);
            a[kt][reg] = v;
            mx = fmaxf(mx, v);
        }
    }
    mx = fmaxf(mx, __shfl_xor(mx, 16));
    mx = fmaxf(mx, __shfl_xor(mx, 32));
    float s = 0.f;
    #pragma unroll
    for (int kt = 0; kt < 4; ++kt)
        #pragma unroll
        for (int reg = 0; reg < 4; ++reg) {
            a[kt][reg] = __expf(a[kt][reg] - mx);
            s += a[kt][reg];
        }
    s += __shfl_xor(s, 16);
    s += __shfl_xor(s, 32);
    const float inv = 1.0f / s;

    u16* dst = attG + (((size_t)b << 18) + ((size_t)n << 6));
    #pragma unroll
    for (int kt = 0; kt < 4; ++kt) {
        ushort4 o;
        o.x = f2bf(a[kt][0] * inv); o.y = f2bf(a[kt][1] * inv);
        o.z = f2bf(a[kt][2] * inv); o.w = f2bf(a[kt][3] * inv);
        *(ushort4*)&dst[kt * 16 + 4 * lg] = o;
    }
}

// ---------------------------------------------------------------------------
// Streaming out kernel: LDS-relaid, line-coalesced epilogue + NT stores.
// Grid dim3(64 ntile, 4 cpair, 8 b), 256 threads, 17 KB LDS.
__global__ __launch_bounds__(256) void out_kernel(
    const float* __restrict__ x1, const float* __restrict__ x2,
    const u16* __restrict__ pv1h, const u16* __restrict__ pv2h,
    const u16* __restrict__ attG,
    const float* __restrict__ scale, const float* __restrict__ scale1,
    float* __restrict__ out1, float* __restrict__ out2)
{
    __shared__ float T[64 * 68];

    const int n0   = blockIdx.x * 64;
    const int cB   = blockIdx.y * 128;
    const int b    = blockIdx.z;
    const int t    = threadIdx.x;
    const int lane = t & 63;
    const int wid  = t >> 6;
    const int lr   = lane & 15;
    const int lg   = lane >> 4;

    // att A-frags, loaded once, reused for both ct and both outputs
    bf16x8 af[4][2];
    #pragma unroll
    for (int nt = 0; nt < 4; ++nt) {
        const u16* ab = attG + (((size_t)b << 18) | ((size_t)(n0 + nt * 16 + lr) << 6)) + lg * 8;
        af[nt][0] = *(const bf16x8*)ab;
        af[nt][1] = *(const bf16x8*)(ab + 32);
    }

    const float sA = scale[0], sB = scale1[0];
    const int er  = t >> 4;          // 0..15
    const int ech = (t & 15) * 4;    // 0..60

    for (int ct = 0; ct < 2; ++ct) {
        const int wc = cB + ct * 64 + wid * 16;

        const u16* p1 = pv1h + (((size_t)(b * Cn + wc + lr)) << 6) + lg * 8;
        const u16* p2 = pv2h + (((size_t)(b * Cn + wc + lr)) << 6) + lg * 8;
        bf16x8 v1[2], v2[2];
        v1[0] = *(const bf16x8*)p1;  v1[1] = *(const bf16x8*)(p1 + 32);
        v2[0] = *(const bf16x8*)p2;  v2[1] = *(const bf16x8*)(p2 + 32);

        f32x4 acc1[4], acc2[4];
        #pragma unroll
        for (int nt = 0; nt < 4; ++nt) {
            f32x4 z = (f32x4){0.f, 0.f, 0.f, 0.f};
            acc1[nt] = __builtin_amdgcn_mfma_f32_16x16x32_bf16(af[nt][0], v1[0], z, 0, 0, 0);
            acc1[nt] = __builtin_amdgcn_mfma_f32_16x16x32_bf16(af[nt][1], v1[1], acc1[nt], 0, 0, 0);
            acc2[nt] = __builtin_amdgcn_mfma_f32_16x16x32_bf16(af[nt][0], v2[0], z, 0, 0, 0);
            acc2[nt] = __builtin_amdgcn_mfma_f32_16x16x32_bf16(af[nt][1], v2[1], acc2[nt], 0, 0, 0);
        }

        // ---- output 1 ----
        __syncthreads();
        #pragma unroll
        for (int nt = 0; nt < 4; ++nt) {
            float4 v;
            v.x = acc1[nt][0]; v.y = acc1[nt][1];
            v.z = acc1[nt][2]; v.w = acc1[nt][3];
            *(float4*)&T[(wid * 16 + lr) * 68 + nt * 16 + 4 * lg] = v;
        }
        __syncthreads();
        #pragma unroll
        for (int pass = 0; pass < 4; ++pass) {
            const int rl = pass * 16 + er;
            const size_t row = (((size_t)(b * Cn + cB + ct * 64 + rl)) << 12) + n0 + ech;
            float4 a = *(const float4*)&T[rl * 68 + ech];
            float4 xv = *(const float4*)&x1[row];
            f32x4 o;
            o[0] = sA * a.x + xv.x;  o[1] = sA * a.y + xv.y;
            o[2] = sA * a.z + xv.z;  o[3] = sA * a.w + xv.w;
            __builtin_nontemporal_store(o, (f32x4*)&out1[row]);
        }

        // ---- output 2 ----
        __syncthreads();
        #pragma unroll
        for (int nt = 0; nt < 4; ++nt) {
            float4 v;
            v.x = acc2[nt][0]; v.y = acc2[nt][1];
            v.z = acc2[nt][2]; v.w = acc2[nt][3];
            *(float4*)&T[(wid * 16 + lr) * 68 + nt * 16 + 4 * lg] = v;
        }
        __syncthreads();
        #pragma unroll
        for (int pass = 0; pass < 4; ++pass) {
            const int rl = pass * 16 + er;
            const size_t row = (((size_t)(b * Cn + cB + ct * 64 + rl)) << 12) + n0 + ech;
            float4 a = *(const float4*)&T[rl * 68 + ech];
            float4 xv = *(const float4*)&x2[row];
            f32x4 o;
            o[0] = sB * a.x + xv.x;  o[1] = sB * a.y + xv.y;
            o[2] = sB * a.z + xv.z;  o[3] = sB * a.w + xv.w;
            __builtin_nontemporal_store(o, (f32x4*)&out2[row]);
        }
    }
}

// ---------------------------------------------------------------------------
extern "C" void kernel_launch(void* const* d_in, const int* in_sizes, int n_in,
                              void* d_out, int out_size, void* d_ws, size_t ws_size,
                              hipStream_t stream)
{
    const float* x1     = (const float*)d_in[0];
    const float* y1     = (const float*)d_in[1];
    const float* x2     = (const float*)d_in[2];
    const float* y2     = (const float*)d_in[3];
    const float* wq     = (const float*)d_in[4];
    const float* bq     = (const float*)d_in[5];
    const float* wk     = (const float*)d_in[6];
    const float* bk     = (const float*)d_in[7];
    const float* wv     = (const float*)d_in[8];
    const float* bv     = (const float*)d_in[9];
    const float* scale  = (const float*)d_in[10];
    const float* scale1 = (const float*)d_in[11];

    float* out1 = (float*)d_out;
    float* out2 = out1 + (size_t)Bn * Cn * Nn;

    float* ws   = (float*)d_ws;
    float* e0   = ws;                       // 512 f
    u16*   kkh  = (u16*)(ws + 512);         // 65536 u16
    u16*   Mth  = kkh + 65536;              // 262144 u16
    u16*   pv1h = Mth + 262144;             // 262144 u16
    u16*   pv2h = pv1h + 262144;            // 262144 u16
    u16*   attG = pv2h + 262144;            // 2097152 u16

    kk_pv_kernel<<<dim3(8, Bn, 3), 256, 0, stream>>>(
        y1, y2, wv, bv, wk, bk, pv1h, pv2h, kkh);
    M_e0_kernel<<<dim3(5, Bn), 256, 0, stream>>>(kkh, wq, bq, Mth, e0);
    energy_softmax_kernel<<<512, 256, 0, stream>>>(x2, Mth, e0, attG);
    out_kernel<<<dim3(64, 4, 8), 256, 0, stream>>>(
        x1, x2, pv1h, pv2h, attG, scale, scale1, out1, out2);
}

// Round 9
// 86.040 us; speedup vs baseline: 2.1956x; 1.0756x over previous
//
#include <hip/hip_runtime.h>
#include <math.h>

#define Bn 8
#define Cn 512
#define Kn 64
#define C4n 128
#define Nn 4096

typedef short bf16x8 __attribute__((ext_vector_type(8)));
typedef float f32x4  __attribute__((ext_vector_type(4)));
typedef unsigned short u16;

__device__ __forceinline__ u16 f2bf(float f) {
    union { float f; unsigned u; } v; v.f = f;
    unsigned r = v.u + 0x7FFF + ((v.u >> 16) & 1);   // RNE
    return (u16)(r >> 16);
}
__device__ __forceinline__ float bf2f(u16 h) {
    union { unsigned u; float f; } v; v.u = ((unsigned)h) << 16;
    return v.f;
}
__device__ __forceinline__ bf16x8 cvt8(const float* p) {
    float4 a = *(const float4*)p;
    float4 b = *(const float4*)(p + 4);
    bf16x8 r;
    r[0] = (short)f2bf(a.x); r[1] = (short)f2bf(a.y);
    r[2] = (short)f2bf(a.z); r[3] = (short)f2bf(a.w);
    r[4] = (short)f2bf(b.x); r[5] = (short)f2bf(b.y);
    r[6] = (short)f2bf(b.z); r[7] = (short)f2bf(b.w);
    return r;
}

// ---------------------------------------------------------------------------
// Merged: z<2 -> pv{z}h[b][c][k] = bf16(sum_c' y{z}[b,k,c']*wv[c,c'] + bv[c])
//         z==2 -> kkh[b][k][d]   = bf16(sum_c' y2[b,k,c']*wk[d,c'] + bk[d])
// Grid dim3(8, 8, 3), 256 threads.
__global__ __launch_bounds__(256) void kk_pv_kernel(
    const float* __restrict__ y1, const float* __restrict__ y2,
    const float* __restrict__ wv, const float* __restrict__ bv,
    const float* __restrict__ wk, const float* __restrict__ bk,
    u16* __restrict__ pv1h, u16* __restrict__ pv2h, u16* __restrict__ kkh)
{
    const int b    = blockIdx.y;
    const int sel  = blockIdx.z;
    const int lane = threadIdx.x & 63;
    const int wid  = threadIdx.x >> 6;
    const int lr   = lane & 15;
    const int lg   = lane >> 4;

    if (sel < 2) {
        const int cb   = blockIdx.x * 64 + wid * 16;
        const float* y = sel ? y2 : y1;
        u16* pvh       = sel ? pv2h : pv1h;

        f32x4 acc[4];
        #pragma unroll
        for (int kt = 0; kt < 4; ++kt) acc[kt] = (f32x4){0.f, 0.f, 0.f, 0.f};

        for (int c0 = 0; c0 < Cn; c0 += 32) {
            const int cf = c0 + lg * 8;
            bf16x8 wfr = cvt8(wv + (size_t)(cb + lr) * Cn + cf);
            bf16x8 yfr[4];
            #pragma unroll
            for (int kt = 0; kt < 4; ++kt)
                yfr[kt] = cvt8(y + (size_t)(b * Kn + kt * 16 + lr) * Cn + cf);
            #pragma unroll
            for (int kt = 0; kt < 4; ++kt)
                acc[kt] = __builtin_amdgcn_mfma_f32_16x16x32_bf16(
                    yfr[kt], wfr, acc[kt], 0, 0, 0);
        }
        const int c = cb + lr;
        const float bb = bv[c];
        #pragma unroll
        for (int kt = 0; kt < 4; ++kt) {
            ushort4 o;
            o.x = f2bf(acc[kt][0] + bb); o.y = f2bf(acc[kt][1] + bb);
            o.z = f2bf(acc[kt][2] + bb); o.w = f2bf(acc[kt][3] + bb);
            *(ushort4*)&pvh[(((size_t)(b * Cn + c)) << 6) + kt * 16 + 4 * lg] = o;
        }
    } else {
        const int dblk = blockIdx.x * 16;
        f32x4 acc = (f32x4){0.f, 0.f, 0.f, 0.f};
        for (int c0 = 0; c0 < Cn; c0 += 32) {
            const int cf = c0 + lg * 8;
            bf16x8 wfr = cvt8(wk + (size_t)(dblk + lr) * Cn + cf);
            bf16x8 yfr = cvt8(y2 + (size_t)(b * Kn + wid * 16 + lr) * Cn + cf);
            acc = __builtin_amdgcn_mfma_f32_16x16x32_bf16(wfr, yfr, acc, 0, 0, 0);
        }
        const int d4 = dblk + 4 * lg;
        float4 bkv = *(const float4*)&bk[d4];
        ushort4 o;
        o.x = f2bf(acc[0] + bkv.x); o.y = f2bf(acc[1] + bkv.y);
        o.z = f2bf(acc[2] + bkv.z); o.w = f2bf(acc[3] + bkv.w);
        *(ushort4*)&kkh[(((size_t)(b * Kn + wid * 16 + lr)) << 7) + d4] = o;
    }
}

// ---------------------------------------------------------------------------
// Merged: x<4 -> Mth[b][k][c] = bf16(sum_d kkh[b][k][d]*wq[d,c])
//         x==4 -> e0[b,k] = sum_d bq[d]*kkh[b][k][d]
// Grid dim3(5, 8), 256 threads.
__global__ __launch_bounds__(256) void M_e0_kernel(
    const u16* __restrict__ kkh, const float* __restrict__ wq,
    const float* __restrict__ bq, u16* __restrict__ Mth,
    float* __restrict__ e0)
{
    const int b = blockIdx.y;
    const int t = threadIdx.x;

    if (blockIdx.x == 4) {
        if (t < Kn) {
            const u16* row = kkh + (((size_t)(b * Kn + t)) << 7);
            float acc = 0.f;
            #pragma unroll
            for (int d8 = 0; d8 < C4n; d8 += 8) {
                bf16x8 v = *(const bf16x8*)(row + d8);
                #pragma unroll
                for (int j = 0; j < 8; ++j)
                    acc += bq[d8 + j] * bf2f((u16)v[j]);
            }
            e0[b * Kn + t] = acc;
        }
        return;
    }

    const int cb   = blockIdx.x * 128 + (t >> 6) * 32;
    const int lane = t & 63;
    const int lr   = lane & 15;
    const int lg   = lane >> 4;

    f32x4 acc[2][4];
    #pragma unroll
    for (int ct = 0; ct < 2; ++ct)
        #pragma unroll
        for (int kt = 0; kt < 4; ++kt) acc[ct][kt] = (f32x4){0.f, 0.f, 0.f, 0.f};

    for (int d0 = 0; d0 < C4n; d0 += 32) {
        const int df = d0 + lg * 8;
        bf16x8 afr[2];
        #pragma unroll
        for (int ct = 0; ct < 2; ++ct) {
            const int c = cb + ct * 16 + lr;
            bf16x8 r;
            #pragma unroll
            for (int j = 0; j < 8; ++j)
                r[j] = (short)f2bf(wq[(size_t)(df + j) * Cn + c]);
            afr[ct] = r;
        }
        bf16x8 bfr[4];
        #pragma unroll
        for (int kt = 0; kt < 4; ++kt)
            bfr[kt] = *(const bf16x8*)&kkh[(((size_t)(b * Kn + kt * 16 + lr)) << 7) + df];
        #pragma unroll
        for (int ct = 0; ct < 2; ++ct)
            #pragma unroll
            for (int kt = 0; kt < 4; ++kt)
                acc[ct][kt] = __builtin_amdgcn_mfma_f32_16x16x32_bf16(
                    afr[ct], bfr[kt], acc[ct][kt], 0, 0, 0);
    }
    #pragma unroll
    for (int ct = 0; ct < 2; ++ct) {
        const int c4 = cb + ct * 16 + 4 * lg;
        #pragma unroll
        for (int kt = 0; kt < 4; ++kt) {
            ushort4 o;
            o.x = f2bf(acc[ct][kt][0]); o.y = f2bf(acc[ct][kt][1]);
            o.z = f2bf(acc[ct][kt][2]); o.w = f2bf(acc[ct][kt][3]);
            *(ushort4*)&Mth[(size_t)(b * Kn + kt * 16 + lr) * Cn + c4] = o;
        }
    }
}

// ---------------------------------------------------------------------------
// Fused attention+output kernel.
// Phase A: energy (operand-swapped MFMA, no staging) + softmax -> attL (LDS,
//          bf16, 16B-chunk XOR swizzle). One __syncthreads.
// Phase B: per-wave independent c-stripes; att frags in regs; per-wave LDS
//          relay T for line-coalesced float4 epilogue; NT stores. No barriers.
// Grid 512 (b = id&7 XCD-affine, 64-n tile = id>>3), 256 threads.
__global__ __launch_bounds__(256) void attn_out_kernel(
    const float* __restrict__ x1, const float* __restrict__ x2,
    const u16* __restrict__ pv1h, const u16* __restrict__ pv2h,
    const u16* __restrict__ Mth, const float* __restrict__ e0,
    const float* __restrict__ scale, const float* __restrict__ scale1,
    float* __restrict__ out1, float* __restrict__ out2)
{
    __shared__ u16   attL[64 * 64];       // swizzled [n][k]
    __shared__ float T[4][16 * 68];       // per-wave epilogue relay

    const int id   = blockIdx.x;
    const int b    = id & 7;
    const int n0   = (id >> 3) * 64;
    const int t    = threadIdx.x;
    const int lane = t & 63;
    const int wid  = t >> 6;
    const int lr   = lane & 15;
    const int lg   = lane >> 4;
    const int nl   = wid * 16 + lr;       // phase-A lane's local n

    // ---------------- Phase A: energy + softmax ----------------
    f32x4 eacc[4];
    #pragma unroll
    for (int kt = 0; kt < 4; ++kt) eacc[kt] = (f32x4){0.f, 0.f, 0.f, 0.f};

    const float* xcol = x2 + (((size_t)b * Cn) << 12) + n0 + nl;  // x2[b][c][n]
    const u16*   mb   = Mth + ((size_t)b << 15) + (size_t)lr * Cn;

    for (int c0 = 0; c0 < Cn; c0 += 32) {
        const int cf = c0 + lg * 8;
        float xs[8];
        #pragma unroll
        for (int j = 0; j < 8; ++j)
            xs[j] = xcol[((size_t)(cf + j)) << 12];
        bf16x8 xfr;
        #pragma unroll
        for (int j = 0; j < 8; ++j) xfr[j] = (short)f2bf(xs[j]);
        #pragma unroll
        for (int kt = 0; kt < 4; ++kt) {
            bf16x8 av = *(const bf16x8*)(mb + ((size_t)kt << 13) + cf);
            eacc[kt] = __builtin_amdgcn_mfma_f32_16x16x32_bf16(av, xfr, eacc[kt], 0, 0, 0);
        }
    }

    {
        float a[4][4];
        float mx = 0.f;   // |.| >= 0
        #pragma unroll
        for (int kt = 0; kt < 4; ++kt) {
            float4 e0v = *(const float4*)&e0[b * Kn + kt * 16 + lg * 4];
            float er[4] = {e0v.x, e0v.y, e0v.z, e0v.w};
            #pragma unroll
            for (int reg = 0; reg < 4; ++reg) {
                float v = fabsf(eacc[kt][reg] + er[reg]);
                a[kt][reg] = v;
                mx = fmaxf(mx, v);
            }
        }
        mx = fmaxf(mx, __shfl_xor(mx, 16));
        mx = fmaxf(mx, __shfl_xor(mx, 32));
        float s = 0.f;
        #pragma unroll
        for (int kt = 0; kt < 4; ++kt)
            #pragma unroll
            for (int reg = 0; reg < 4; ++reg) {
                a[kt][reg] = __expf(a[kt][reg] - mx);
                s += a[kt][reg];
            }
        s += __shfl_xor(s, 16);
        s += __shfl_xor(s, 32);
        const float inv = 1.0f / s;

        // store att row nl: k = kt*16 + 4*lg + {0..3}; chunk-XOR swizzle
        #pragma unroll
        for (int kt = 0; kt < 4; ++kt) {
            ushort4 o;
            o.x = f2bf(a[kt][0] * inv); o.y = f2bf(a[kt][1] * inv);
            o.z = f2bf(a[kt][2] * inv); o.w = f2bf(a[kt][3] * inv);
            const int chunk = (kt * 2 + (lg >> 1)) ^ (nl & 7);
            *(ushort4*)&attL[nl * 64 + chunk * 8 + 4 * (lg & 1)] = o;
        }
    }
    __syncthreads();

    // ---------------- Phase B: out tiles, per-wave independent ----------------
    // att A-frags: A[row=n=nt*16+lr][k = ks*32 + lg*8 + j]
    bf16x8 af[4][2];
    #pragma unroll
    for (int nt = 0; nt < 4; ++nt)
        #pragma unroll
        for (int ks = 0; ks < 2; ++ks) {
            const int nn = nt * 16 + lr;
            const int chunk = (ks * 4 + lg) ^ (nn & 7);
            af[nt][ks] = *(const bf16x8*)&attL[nn * 64 + chunk * 8];
        }

    const float sA = scale[0], sB = scale1[0];
    float* Tw = &T[wid][0];

    for (int ct = 0; ct < 8; ++ct) {
        const int wc = ct * 64 + wid * 16;    // wave's 16-c stripe

        const u16* p1 = pv1h + (((size_t)(b * Cn + wc + lr)) << 6) + lg * 8;
        const u16* p2 = pv2h + (((size_t)(b * Cn + wc + lr)) << 6) + lg * 8;
        bf16x8 v1[2], v2[2];
        v1[0] = *(const bf16x8*)p1;  v1[1] = *(const bf16x8*)(p1 + 32);
        v2[0] = *(const bf16x8*)p2;  v2[1] = *(const bf16x8*)(p2 + 32);

        f32x4 acc1[4], acc2[4];
        #pragma unroll
        for (int nt = 0; nt < 4; ++nt) {
            f32x4 z = (f32x4){0.f, 0.f, 0.f, 0.f};
            acc1[nt] = __builtin_amdgcn_mfma_f32_16x16x32_bf16(af[nt][0], v1[0], z, 0, 0, 0);
            acc1[nt] = __builtin_amdgcn_mfma_f32_16x16x32_bf16(af[nt][1], v1[1], acc1[nt], 0, 0, 0);
            acc2[nt] = __builtin_amdgcn_mfma_f32_16x16x32_bf16(af[nt][0], v2[0], z, 0, 0, 0);
            acc2[nt] = __builtin_amdgcn_mfma_f32_16x16x32_bf16(af[nt][1], v2[1], acc2[nt], 0, 0, 0);
        }

        // ---- output 1: per-wave stage -> coalesced drain ----
        #pragma unroll
        for (int nt = 0; nt < 4; ++nt) {
            float4 v;
            v.x = acc1[nt][0]; v.y = acc1[nt][1];
            v.z = acc1[nt][2]; v.w = acc1[nt][3];
            *(float4*)&Tw[lr * 68 + nt * 16 + 4 * lg] = v;
        }
        #pragma unroll
        for (int r4 = 0; r4 < 4; ++r4) {
            const int rloc = r4 * 4 + lg;
            const size_t row = (((size_t)(b * Cn + wc + rloc)) << 12) + n0 + lr * 4;
            float4 a = *(const float4*)&Tw[rloc * 68 + lr * 4];
            float4 xv = *(const float4*)&x1[row];
            f32x4 o;
            o[0] = sA * a.x + xv.x;  o[1] = sA * a.y + xv.y;
            o[2] = sA * a.z + xv.z;  o[3] = sA * a.w + xv.w;
            __builtin_nontemporal_store(o, (f32x4*)&out1[row]);
        }

        // ---- output 2 ----
        #pragma unroll
        for (int nt = 0; nt < 4; ++nt) {
            float4 v;
            v.x = acc2[nt][0]; v.y = acc2[nt][1];
            v.z = acc2[nt][2]; v.w = acc2[nt][3];
            *(float4*)&Tw[lr * 68 + nt * 16 + 4 * lg] = v;
        }
        #pragma unroll
        for (int r4 = 0; r4 < 4; ++r4) {
            const int rloc = r4 * 4 + lg;
            const size_t row = (((size_t)(b * Cn + wc + rloc)) << 12) + n0 + lr * 4;
            float4 a = *(const float4*)&Tw[rloc * 68 + lr * 4];
            float4 xv = *(const float4*)&x2[row];
            f32x4 o;
            o[0] = sB * a.x + xv.x;  o[1] = sB * a.y + xv.y;
            o[2] = sB * a.z + xv.z;  o[3] = sB * a.w + xv.w;
            __builtin_nontemporal_store(o, (f32x4*)&out2[row]);
        }
    }
}

// ---------------------------------------------------------------------------
extern "C" void kernel_launch(void* const* d_in, const int* in_sizes, int n_in,
                              void* d_out, int out_size, void* d_ws, size_t ws_size,
                              hipStream_t stream)
{
    const float* x1     = (const float*)d_in[0];
    const float* y1     = (const float*)d_in[1];
    const float* x2     = (const float*)d_in[2];
    const float* y2     = (const float*)d_in[3];
    const float* wq     = (const float*)d_in[4];
    const float* bq     = (const float*)d_in[5];
    const float* wk     = (const float*)d_in[6];
    const float* bk     = (const float*)d_in[7];
    const float* wv     = (const float*)d_in[8];
    const float* bv     = (const float*)d_in[9];
    const float* scale  = (const float*)d_in[10];
    const float* scale1 = (const float*)d_in[11];

    float* out1 = (float*)d_out;
    float* out2 = out1 + (size_t)Bn * Cn * Nn;

    float* ws   = (float*)d_ws;
    float* e0   = ws;                       // 512 f
    u16*   kkh  = (u16*)(ws + 512);         // 65536 u16
    u16*   Mth  = kkh + 65536;              // 262144 u16
    u16*   pv1h = Mth + 262144;             // 262144 u16
    u16*   pv2h = pv1h + 262144;            // 262144 u16

    kk_pv_kernel<<<dim3(8, Bn, 3), 256, 0, stream>>>(
        y1, y2, wv, bv, wk, bk, pv1h, pv2h, kkh);
    M_e0_kernel<<<dim3(5, Bn), 256, 0, stream>>>(kkh, wq, bq, Mth, e0);
    attn_out_kernel<<<512, 256, 0, stream>>>(
        x1, x2, pv1h, pv2h, Mth, e0, scale, scale1, out1, out2);
}